// Round 4
// baseline (1036.220 us; speedup 1.0000x reference)
//
#include <hip/hip_runtime.h>
#include <hip/hip_bf16.h>

// Problem constants (match reference setup_inputs)
#define N_NODE_C  50000
#define N_TOT_C   100000   // N_NODE + N_ATTRI
#define D_C       128
#define E_EDGES_C 1600000
#define E_PAIR_C  50000

// ---------------------------------------------------------------------------
// CSR build: counts -> exclusive scan -> scatter permutation.
// Rebuilt every call (ws is re-poisoned before every timed launch).
// ---------------------------------------------------------------------------
__global__ void k_count(const int* __restrict__ row, int* __restrict__ cnt) {
  int e = blockIdx.x * 256 + threadIdx.x;
  if (e < E_EDGES_C) atomicAdd(&cnt[row[e]], 1);
}

// Single-block scan over 100000 counts. Writes row_ptr[0..N] and resets
// cnt[i] to the row start (cursor for the scatter phase).
// 1000 active threads x 100 elems; int4 loads. Pass 2 RE-READS cnt (L2-hot,
// ~400KB) instead of caching 100 ints in registers: keeps VGPRs ~40 so the
// 16-wave workgroup is schedulable (>=128 VGPR would cap the CU at <16 waves).
__global__ __launch_bounds__(1024) void k_scan(int* cnt, int* __restrict__ row_ptr) {
  __shared__ int part[1024];
  const int tid = threadIdx.x;
  const int CH = 100;                    // 1000 threads cover 100000 exactly
  const int b = tid * CH;
  const bool act = (b < N_TOT_C);        // tid < 1000
  int s = 0;
  if (act) {
    const int4* c4 = (const int4*)(cnt + b);
#pragma unroll
    for (int i = 0; i < 25; ++i) {
      int4 c = c4[i];
      s += c.x + c.y + c.z + c.w;
    }
  }
  part[tid] = s;
  __syncthreads();
  // inclusive Hillis-Steele scan of 1024 partials
  for (int off = 1; off < 1024; off <<= 1) {
    int v = (tid >= off) ? part[tid - off] : 0;
    __syncthreads();
    part[tid] += v;
    __syncthreads();
  }
  if (tid == 1023) row_ptr[N_TOT_C] = part[1023];  // == E_EDGES
  if (act) {
    int run = (tid == 0) ? 0 : part[tid - 1];
    const int4* c4 = (const int4*)(cnt + b);
    int4* rp4 = (int4*)(row_ptr + b);
    int4* cn4 = (int4*)(cnt + b);
#pragma unroll
    for (int i = 0; i < 25; ++i) {
      int4 c = c4[i];            // re-read (still L2-resident)
      int4 o;
      o.x = run;
      o.y = run + c.x;
      o.z = run + c.x + c.y;
      o.w = run + c.x + c.y + c.z;
      rp4[i] = o;   // exclusive row starts
      cn4[i] = o;   // cursor for scatter
      run += c.x + c.y + c.z + c.w;
    }
  }
}

// Scatter edges into CSR slots. Metadata stored interleaved as int2
// {col, bitcast(val)}: ONE 8B scattered store per edge (vs two 4B).
__global__ void k_scatter(const int* __restrict__ row, const int* __restrict__ col,
                          const float* __restrict__ val, int* cursor,
                          int2* __restrict__ cpair) {
  int e = blockIdx.x * 256 + threadIdx.x;
  if (e < E_EDGES_C) {
    int r = row[e];
    int slot = atomicAdd(&cursor[r], 1);
    cpair[slot] = make_int2(col[e], __float_as_int(val[e]));
  }
}

// ---------------------------------------------------------------------------
// Dense GEMM: out[N,128] = x[N,128] @ W[128,128]  (fp32, vector ALU).
// x is the concat (srcA rows [0,split), srcB rows [split,N)).
// Block: 256 threads, 32 rows. W in LDS (64KB -> 2 blocks/CU, 8 waves/CU).
// x read straight from global: xv depends only on rg, so 32 lanes share one
// 16B address (broadcast-coalesced, L1-resident 16KB/block) — no LDS stage.
// Each thread computes a 4x4 register tile.
// ---------------------------------------------------------------------------
__global__ __launch_bounds__(256) void k_gemm(const float* __restrict__ srcA,
                                              const float* __restrict__ srcB,
                                              int split, const float* __restrict__ W,
                                              float* __restrict__ out) {
  __shared__ float Wl[128 * 128];
  const int tid = threadIdx.x;
  {
    const float4* W4 = (const float4*)W;
    float4* Wl4 = (float4*)Wl;
#pragma unroll
    for (int i = 0; i < 16; ++i) Wl4[tid + i * 256] = W4[tid + i * 256];
  }
  __syncthreads();
  const int cg = tid & 31, rg = tid >> 5;  // 32 col-groups x 8 row-groups
  const int rowbase = blockIdx.x * 32;
  const float* xr[4];
#pragma unroll
  for (int r = 0; r < 4; ++r) {
    int gr = rowbase + rg * 4 + r;
    xr[r] = (gr < split) ? (srcA + (size_t)gr * D_C)
                         : (srcB + (size_t)(gr - split) * D_C);
  }
  float acc[4][4] = {};
  for (int k4 = 0; k4 < 128; k4 += 4) {
    float4 wv[4], xv[4];
#pragma unroll
    for (int j = 0; j < 4; ++j) wv[j] = *(const float4*)&Wl[(k4 + j) * 128 + cg * 4];
#pragma unroll
    for (int r = 0; r < 4; ++r) xv[r] = *(const float4*)&xr[r][k4];
#pragma unroll
    for (int r = 0; r < 4; ++r) {
      acc[r][0] += xv[r].x * wv[0].x + xv[r].y * wv[1].x + xv[r].z * wv[2].x + xv[r].w * wv[3].x;
      acc[r][1] += xv[r].x * wv[0].y + xv[r].y * wv[1].y + xv[r].z * wv[2].y + xv[r].w * wv[3].y;
      acc[r][2] += xv[r].x * wv[0].z + xv[r].y * wv[1].z + xv[r].z * wv[2].z + xv[r].w * wv[3].z;
      acc[r][3] += xv[r].x * wv[0].w + xv[r].y * wv[1].w + xv[r].z * wv[2].w + xv[r].w * wv[3].w;
    }
  }
#pragma unroll
  for (int r = 0; r < 4; ++r) {
    float4 o;
    o.x = acc[r][0]; o.y = acc[r][1]; o.z = acc[r][2]; o.w = acc[r][3];
    *(float4*)&out[(size_t)(rowbase + rg * 4 + r) * D_C + cg * 4] = o;
  }
}

// ---------------------------------------------------------------------------
// SpMM (CSR): xout[r,:] = sum_e val[e] * sup[col[e],:] + bias.
// One 64-lane wave per row; float2 per lane (covers D=128); unroll-by-4 so
// 8 independent gathers are in flight per wave (L2/L3 latency ~200-900cy).
// Row id forced wave-uniform via readfirstlane so row_ptr/cpair loads can
// take the scalar path (SGPR base + s_load), freeing VMEM for the gathers.
// ---------------------------------------------------------------------------
__global__ __launch_bounds__(256) void k_spmm(const int* __restrict__ row_ptr,
                                              const int2* __restrict__ cpair,
                                              const float* __restrict__ sup,
                                              const float* __restrict__ bias,
                                              float* __restrict__ xout) {
  int wave = (blockIdx.x * 256 + threadIdx.x) >> 6;
  wave = __builtin_amdgcn_readfirstlane(wave);
  int lane = threadIdx.x & 63;
  if (wave >= N_TOT_C) return;
  int s = row_ptr[wave], e = row_ptr[wave + 1];
  float a0 = 0.f, a1 = 0.f;
  int i = s;
  for (; i + 3 < e; i += 4) {
    int2 p0 = cpair[i], p1 = cpair[i + 1], p2 = cpair[i + 2], p3 = cpair[i + 3];
    float2 s0 = *(const float2*)&sup[(size_t)p0.x * D_C + lane * 2];
    float2 s1 = *(const float2*)&sup[(size_t)p1.x * D_C + lane * 2];
    float2 s2 = *(const float2*)&sup[(size_t)p2.x * D_C + lane * 2];
    float2 s3 = *(const float2*)&sup[(size_t)p3.x * D_C + lane * 2];
    float v0 = __int_as_float(p0.y), v1 = __int_as_float(p1.y);
    float v2 = __int_as_float(p2.y), v3 = __int_as_float(p3.y);
    a0 += v0 * s0.x + v1 * s1.x + v2 * s2.x + v3 * s3.x;
    a1 += v0 * s0.y + v1 * s1.y + v2 * s2.y + v3 * s3.y;
  }
  for (; i < e; ++i) {
    int2 p0 = cpair[i];
    float2 s0 = *(const float2*)&sup[(size_t)p0.x * D_C + lane * 2];
    float v0 = __int_as_float(p0.y);
    a0 += v0 * s0.x;
    a1 += v0 * s0.y;
  }
  float2 bb = *(const float2*)&bias[lane * 2];
  *(float2*)&xout[(size_t)wave * D_C + lane * 2] = make_float2(a0 + bb.x, a1 + bb.y);
}

// ---------------------------------------------------------------------------
// Gather + L2-normalize: out[s,hop,i,:] = l2norm(x[idx_s[i],:]).
// One wave per row; float2 per lane; 6-step shfl_xor sum-of-squares reduce.
// grid.y = stream (pos_src, pos_dst, neg_src, neg_dst).
// ---------------------------------------------------------------------------
__global__ __launch_bounds__(256) void k_gnorm(const float* __restrict__ srcA,
                                               const float* __restrict__ srcB,
                                               int split,
                                               const int* __restrict__ i0,
                                               const int* __restrict__ i1,
                                               const int* __restrict__ i2,
                                               const int* __restrict__ i3,
                                               float* __restrict__ out, int hop) {
  int sidx = blockIdx.y;
  const int* idx = (sidx == 0) ? i0 : (sidx == 1) ? i1 : (sidx == 2) ? i2 : i3;
  int wid = (blockIdx.x * 256 + threadIdx.x) >> 6;
  wid = __builtin_amdgcn_readfirstlane(wid);
  int lane = threadIdx.x & 63;
  if (wid >= E_PAIR_C) return;
  int g = idx[wid];
  const float* src = (g < split) ? (srcA + (size_t)g * D_C)
                                 : (srcB + (size_t)(g - split) * D_C);
  float2 v = *(const float2*)&src[lane * 2];
  float ss = v.x * v.x + v.y * v.y;
#pragma unroll
  for (int off = 32; off; off >>= 1) ss += __shfl_xor(ss, off, 64);
  float scale = 1.0f / fmaxf(sqrtf(ss), 1e-12f);
  size_t o = (((size_t)sidx * 3 + hop) * E_PAIR_C + wid) * D_C + lane * 2;
  *(float2*)&out[o] = make_float2(v.x * scale, v.y * scale);
}

// ---------------------------------------------------------------------------
// Workspace layout (bytes), all offsets 16B-aligned. Requires ~116 MB ws.
//   buf0    @ 0          : N*D f32 (51.2 MB)   x after each spmm
//   buf1    @ 51200000   : N*D f32 (51.2 MB)   support = x @ W
//   row_ptr @ 102400000  : (N+1) i32
//   cnt     @ 102800128  : N i32 (counts, then cursor)
//   cpair   @ 103200128  : E int2 {col, bitcast val} (12.8 MB; end 116000128)
// ---------------------------------------------------------------------------
extern "C" void kernel_launch(void* const* d_in, const int* in_sizes, int n_in,
                              void* d_out, int out_size, void* d_ws, size_t ws_size,
                              hipStream_t stream) {
  const float* node  = (const float*)d_in[0];
  const float* attri = (const float*)d_in[1];
  const float* W1 = (const float*)d_in[2];
  const float* b1 = (const float*)d_in[3];
  const float* W2 = (const float*)d_in[4];
  const float* b2 = (const float*)d_in[5];
  const float* eval_ = (const float*)d_in[6];
  const int* erow = (const int*)d_in[7];
  const int* ecol = (const int*)d_in[8];
  const int* ps = (const int*)d_in[9];
  const int* pd = (const int*)d_in[10];
  const int* ns = (const int*)d_in[11];
  const int* nd = (const int*)d_in[12];
  float* out = (float*)d_out;

  char* ws = (char*)d_ws;
  float* buf0    = (float*)(ws);
  float* buf1    = (float*)(ws + 51200000);
  int*   row_ptr = (int*)  (ws + 102400000);
  int*   cnt     = (int*)  (ws + 102800128);
  int2*  cpair   = (int2*) (ws + 103200128);

  // --- CSR build (shared by both layers) ---
  hipMemsetAsync(cnt, 0, N_TOT_C * sizeof(int), stream);
  k_count<<<E_EDGES_C / 256, 256, 0, stream>>>(erow, cnt);
  k_scan<<<1, 1024, 0, stream>>>(cnt, row_ptr);
  k_scatter<<<E_EDGES_C / 256, 256, 0, stream>>>(erow, ecol, eval_, cnt, cpair);

  dim3 gn(E_PAIR_C / 4, 4);

  // hop 0: normalize gathers of the raw concat embedding
  k_gnorm<<<gn, 256, 0, stream>>>(node, attri, N_NODE_C, ps, pd, ns, nd, out, 0);

  // layer 1: support = x @ W1 ; x = spmm(adj, support) + b1
  k_gemm<<<N_TOT_C / 32, 256, 0, stream>>>(node, attri, N_NODE_C, W1, buf1);
  k_spmm<<<N_TOT_C / 4, 256, 0, stream>>>(row_ptr, cpair, buf1, b1, buf0);
  k_gnorm<<<gn, 256, 0, stream>>>(buf0, buf0 + (size_t)N_NODE_C * D_C, N_NODE_C,
                                  ps, pd, ns, nd, out, 1);

  // layer 2
  k_gemm<<<N_TOT_C / 32, 256, 0, stream>>>(buf0, buf0 + (size_t)N_NODE_C * D_C,
                                           N_NODE_C, W2, buf1);
  k_spmm<<<N_TOT_C / 4, 256, 0, stream>>>(row_ptr, cpair, buf1, b2, buf0);
  k_gnorm<<<gn, 256, 0, stream>>>(buf0, buf0 + (size_t)N_NODE_C * D_C, N_NODE_C,
                                  ps, pd, ns, nd, out, 2);
}

// Round 6
// 1015.177 us; speedup vs baseline: 1.0207x; 1.0207x over previous
//
#include <hip/hip_runtime.h>
#include <hip/hip_bf16.h>

// Problem constants (match reference setup_inputs)
#define N_NODE_C  50000
#define N_TOT_C   100000   // N_NODE + N_ATTRI
#define D_C       128
#define E_EDGES_C 1600000
#define E_PAIR_C  50000

// ---------------------------------------------------------------------------
// CSR build: counts -> exclusive scan -> scatter permutation.
// ---------------------------------------------------------------------------
__global__ void k_count(const int* __restrict__ row, int* __restrict__ cnt) {
  int e = blockIdx.x * 256 + threadIdx.x;
  if (e < E_EDGES_C) atomicAdd(&cnt[row[e]], 1);
}

// Single-block scan over 100000 counts -> row_ptr + cursor (cnt reused).
// Pass 2 re-reads cnt (L2-hot) to keep VGPRs low (16-wave block schedulable).
__global__ __launch_bounds__(1024) void k_scan(int* cnt, int* __restrict__ row_ptr) {
  __shared__ int part[1024];
  const int tid = threadIdx.x;
  const int CH = 100;                    // 1000 threads cover 100000 exactly
  const int b = tid * CH;
  const bool act = (b < N_TOT_C);        // tid < 1000
  int s = 0;
  if (act) {
    const int4* c4 = (const int4*)(cnt + b);
#pragma unroll
    for (int i = 0; i < 25; ++i) {
      int4 c = c4[i];
      s += c.x + c.y + c.z + c.w;
    }
  }
  part[tid] = s;
  __syncthreads();
  for (int off = 1; off < 1024; off <<= 1) {
    int v = (tid >= off) ? part[tid - off] : 0;
    __syncthreads();
    part[tid] += v;
    __syncthreads();
  }
  if (tid == 1023) row_ptr[N_TOT_C] = part[1023];  // == E_EDGES
  if (act) {
    int run = (tid == 0) ? 0 : part[tid - 1];
    const int4* c4 = (const int4*)(cnt + b);
    int4* rp4 = (int4*)(row_ptr + b);
    int4* cn4 = (int4*)(cnt + b);
#pragma unroll
    for (int i = 0; i < 25; ++i) {
      int4 c = c4[i];            // re-read (still L2-resident)
      int4 o;
      o.x = run;
      o.y = run + c.x;
      o.z = run + c.x + c.y;
      o.w = run + c.x + c.y + c.z;
      rp4[i] = o;   // exclusive row starts
      cn4[i] = o;   // cursor for scatter
      run += c.x + c.y + c.z + c.w;
    }
  }
}

// Scatter edges into CSR slots as interleaved int2 {col, bitcast(val)}.
__global__ void k_scatter(const int* __restrict__ row, const int* __restrict__ col,
                          const float* __restrict__ val, int* cursor,
                          int2* __restrict__ cpair) {
  int e = blockIdx.x * 256 + threadIdx.x;
  if (e < E_EDGES_C) {
    int r = row[e];
    int slot = atomicAdd(&cursor[r], 1);
    cpair[slot] = make_int2(col[e], __float_as_int(val[e]));
  }
}

// ---------------------------------------------------------------------------
// Dense GEMM: out[N,128] = x[N,128] @ W[128,128]  (fp32, vector ALU).
// W in LDS (64KB -> 2 blocks/CU); x broadcast-read from global (L1-resident).
// ---------------------------------------------------------------------------
__global__ __launch_bounds__(256) void k_gemm(const float* __restrict__ srcA,
                                              const float* __restrict__ srcB,
                                              int split, const float* __restrict__ W,
                                              float* __restrict__ out) {
  __shared__ float Wl[128 * 128];
  const int tid = threadIdx.x;
  {
    const float4* W4 = (const float4*)W;
    float4* Wl4 = (float4*)Wl;
#pragma unroll
    for (int i = 0; i < 16; ++i) Wl4[tid + i * 256] = W4[tid + i * 256];
  }
  __syncthreads();
  const int cg = tid & 31, rg = tid >> 5;  // 32 col-groups x 8 row-groups
  const int rowbase = blockIdx.x * 32;
  const float* xr[4];
#pragma unroll
  for (int r = 0; r < 4; ++r) {
    int gr = rowbase + rg * 4 + r;
    xr[r] = (gr < split) ? (srcA + (size_t)gr * D_C)
                         : (srcB + (size_t)(gr - split) * D_C);
  }
  float acc[4][4] = {};
  for (int k4 = 0; k4 < 128; k4 += 4) {
    float4 wv[4], xv[4];
#pragma unroll
    for (int j = 0; j < 4; ++j) wv[j] = *(const float4*)&Wl[(k4 + j) * 128 + cg * 4];
#pragma unroll
    for (int r = 0; r < 4; ++r) xv[r] = *(const float4*)&xr[r][k4];
#pragma unroll
    for (int r = 0; r < 4; ++r) {
      acc[r][0] += xv[r].x * wv[0].x + xv[r].y * wv[1].x + xv[r].z * wv[2].x + xv[r].w * wv[3].x;
      acc[r][1] += xv[r].x * wv[0].y + xv[r].y * wv[1].y + xv[r].z * wv[2].y + xv[r].w * wv[3].y;
      acc[r][2] += xv[r].x * wv[0].z + xv[r].y * wv[1].z + xv[r].z * wv[2].z + xv[r].w * wv[3].z;
      acc[r][3] += xv[r].x * wv[0].w + xv[r].y * wv[1].w + xv[r].z * wv[2].w + xv[r].w * wv[3].w;
    }
  }
#pragma unroll
  for (int r = 0; r < 4; ++r) {
    float4 o;
    o.x = acc[r][0]; o.y = acc[r][1]; o.z = acc[r][2]; o.w = acc[r][3];
    *(float4*)&out[(size_t)(rowbase + rg * 4 + r) * D_C + cg * 4] = o;
  }
}

// ---------------------------------------------------------------------------
// SpMM (CSR): xout[r,:] = sum_e val[e] * sup[col[e],:] + bias.
// One wave per row. D=128 on 32 lanes x float4 (16B/lane sweet spot, one
// 512B request per edge); the wave's two 32-lane halves process edges i and
// i+1 simultaneously (2 edges per gather step -> half the latency chain).
// Metadata loaded as int2 per edge (8B-aligned ALWAYS — row starts can be
// odd, so an int4 load at &cpair[i] would be under-aligned UB).
// Final shfl_xor(32) merges the two half-wave partial sums.
// ---------------------------------------------------------------------------
__global__ __launch_bounds__(256) void k_spmm(const int* __restrict__ row_ptr,
                                              const int2* __restrict__ cpair,
                                              const float* __restrict__ sup,
                                              const float* __restrict__ bias,
                                              float* __restrict__ xout) {
  int wave = (blockIdx.x * 256 + threadIdx.x) >> 6;
  wave = __builtin_amdgcn_readfirstlane(wave);
  if (wave >= N_TOT_C) return;
  const int lane = threadIdx.x & 63;
  const int half = lane >> 5;      // 0: edge i, 1: edge i+1
  const int q = lane & 31;         // float4 slot: floats [q*4, q*4+4)
  int s = row_ptr[wave], e = row_ptr[wave + 1];
  float4 acc = make_float4(0.f, 0.f, 0.f, 0.f);
  int i = s;
  for (; i + 3 < e; i += 4) {      // 4 edges: 4 uniform int2 loads, 2 gathers
    int2 pa0 = cpair[i],     pa1 = cpair[i + 1];
    int2 pb0 = cpair[i + 2], pb1 = cpair[i + 3];
    int ca = half ? pa1.x : pa0.x;
    int cb = half ? pb1.x : pb0.x;
    float va = __int_as_float(half ? pa1.y : pa0.y);
    float vb = __int_as_float(half ? pb1.y : pb0.y);
    float4 ga = *(const float4*)&sup[(size_t)ca * D_C + q * 4];
    float4 gb = *(const float4*)&sup[(size_t)cb * D_C + q * 4];
    acc.x += va * ga.x + vb * gb.x;
    acc.y += va * ga.y + vb * gb.y;
    acc.z += va * ga.z + vb * gb.z;
    acc.w += va * ga.w + vb * gb.w;
  }
  for (; i < e; i += 2) {          // pair (or guarded tail single)
    int2 p0 = cpair[i];
    int c1 = p0.x; float v1 = 0.f;
    if (i + 1 < e) { int2 p1 = cpair[i + 1]; c1 = p1.x; v1 = __int_as_float(p1.y); }
    int c = half ? c1 : p0.x;
    float v = half ? v1 : __int_as_float(p0.y);
    float4 g = *(const float4*)&sup[(size_t)c * D_C + q * 4];
    acc.x += v * g.x; acc.y += v * g.y; acc.z += v * g.z; acc.w += v * g.w;
  }
  acc.x += __shfl_xor(acc.x, 32, 64);
  acc.y += __shfl_xor(acc.y, 32, 64);
  acc.z += __shfl_xor(acc.z, 32, 64);
  acc.w += __shfl_xor(acc.w, 32, 64);
  if (half == 0) {
    float4 bb = *(const float4*)&bias[q * 4];
    float4 o = make_float4(acc.x + bb.x, acc.y + bb.y, acc.z + bb.z, acc.w + bb.w);
    *(float4*)&xout[(size_t)wave * D_C + q * 4] = o;
  }
}

// ---------------------------------------------------------------------------
// Gather + L2-normalize: out[s,hop,j,:] = l2norm(x[idx_s[j],:]).
// Two rows per wave (one per 32-lane half), float4 per lane for the gather
// and the (mandatory 307MB) dwordx4 store; 5-step half-wave shfl reduce.
// ---------------------------------------------------------------------------
__global__ __launch_bounds__(256) void k_gnorm(const float* __restrict__ srcA,
                                               const float* __restrict__ srcB,
                                               int split,
                                               const int* __restrict__ i0,
                                               const int* __restrict__ i1,
                                               const int* __restrict__ i2,
                                               const int* __restrict__ i3,
                                               float* __restrict__ out, int hop) {
  int sidx = blockIdx.y;
  const int* idx = (sidx == 0) ? i0 : (sidx == 1) ? i1 : (sidx == 2) ? i2 : i3;
  int wave = (blockIdx.x * 256 + threadIdx.x) >> 6;
  const int lane = threadIdx.x & 63;
  const int half = lane >> 5, q = lane & 31;
  int j = wave * 2 + half;
  if (j >= E_PAIR_C) return;
  int g = idx[j];
  const float* src = (g < split) ? (srcA + (size_t)g * D_C)
                                 : (srcB + (size_t)(g - split) * D_C);
  float4 v = *(const float4*)&src[q * 4];
  float ss = v.x * v.x + v.y * v.y + v.z * v.z + v.w * v.w;
#pragma unroll
  for (int off = 16; off; off >>= 1) ss += __shfl_xor(ss, off, 64);  // within half
  float scale = 1.0f / fmaxf(sqrtf(ss), 1e-12f);
  size_t o = (((size_t)sidx * 3 + hop) * E_PAIR_C + j) * D_C + q * 4;
  *(float4*)&out[o] = make_float4(v.x * scale, v.y * scale, v.z * scale, v.w * scale);
}

// ---------------------------------------------------------------------------
// Workspace layout (bytes). Requires ~116 MB ws.
//   buf0    @ 0          : N*D f32 (51.2 MB)
//   buf1    @ 51200000   : N*D f32 (51.2 MB)
//   row_ptr @ 102400000  : (N+1) i32
//   cnt     @ 102800128  : N i32 (counts, then cursor)
//   cpair   @ 103200128  : E int2 {col, bitcast val} (12.8 MB; end 116000128)
// ---------------------------------------------------------------------------
extern "C" void kernel_launch(void* const* d_in, const int* in_sizes, int n_in,
                              void* d_out, int out_size, void* d_ws, size_t ws_size,
                              hipStream_t stream) {
  const float* node  = (const float*)d_in[0];
  const float* attri = (const float*)d_in[1];
  const float* W1 = (const float*)d_in[2];
  const float* b1 = (const float*)d_in[3];
  const float* W2 = (const float*)d_in[4];
  const float* b2 = (const float*)d_in[5];
  const float* eval_ = (const float*)d_in[6];
  const int* erow = (const int*)d_in[7];
  const int* ecol = (const int*)d_in[8];
  const int* ps = (const int*)d_in[9];
  const int* pd = (const int*)d_in[10];
  const int* ns = (const int*)d_in[11];
  const int* nd = (const int*)d_in[12];
  float* out = (float*)d_out;

  char* ws = (char*)d_ws;
  float* buf0    = (float*)(ws);
  float* buf1    = (float*)(ws + 51200000);
  int*   row_ptr = (int*)  (ws + 102400000);
  int*   cnt     = (int*)  (ws + 102800128);
  int2*  cpair   = (int2*) (ws + 103200128);

  // --- CSR build (shared by both layers) ---
  hipMemsetAsync(cnt, 0, N_TOT_C * sizeof(int), stream);
  k_count<<<E_EDGES_C / 256, 256, 0, stream>>>(erow, cnt);
  k_scan<<<1, 1024, 0, stream>>>(cnt, row_ptr);
  k_scatter<<<E_EDGES_C / 256, 256, 0, stream>>>(erow, ecol, eval_, cnt, cpair);

  dim3 gn(E_PAIR_C / 8, 4);   // 2 rows/wave, 4 waves/block -> 6250 blocks

  // hop 0: normalize gathers of the raw concat embedding
  k_gnorm<<<gn, 256, 0, stream>>>(node, attri, N_NODE_C, ps, pd, ns, nd, out, 0);

  // layer 1: support = x @ W1 ; x = spmm(adj, support) + b1
  k_gemm<<<N_TOT_C / 32, 256, 0, stream>>>(node, attri, N_NODE_C, W1, buf1);
  k_spmm<<<N_TOT_C / 4, 256, 0, stream>>>(row_ptr, cpair, buf1, b1, buf0);
  k_gnorm<<<gn, 256, 0, stream>>>(buf0, buf0 + (size_t)N_NODE_C * D_C, N_NODE_C,
                                  ps, pd, ns, nd, out, 1);

  // layer 2
  k_gemm<<<N_TOT_C / 32, 256, 0, stream>>>(buf0, buf0 + (size_t)N_NODE_C * D_C,
                                           N_NODE_C, W2, buf1);
  k_spmm<<<N_TOT_C / 4, 256, 0, stream>>>(row_ptr, cpair, buf1, b2, buf0);
  k_gnorm<<<gn, 256, 0, stream>>>(buf0, buf0 + (size_t)N_NODE_C * D_C, N_NODE_C,
                                  ps, pd, ns, nd, out, 2);
}